// Round 1
// baseline (109.407 us; speedup 1.0000x reference)
//
#include <hip/hip_runtime.h>

// out[r][c] = (float)weight[r][c] * scale[r]
// weight: int32 container holding int8 values, shape (8192, 8192)
// scale:  f32, shape (8192, 1)
// out:    f32, shape (8192, 8192)
//
// Memory-bound: 256 MB read + 256 MB write. Vectorize as int4 -> float4
// (16 B per lane). Row index derived from vector-group index via shift
// (IN/4 is a power of two for this problem).

__global__ __launch_bounds__(256) void decompress_int8_sym_kernel(
    const int4* __restrict__ w4,
    const float* __restrict__ scale,
    float4* __restrict__ out4,
    int n4,           // total int4 groups = OUT*IN/4
    int row_shift)    // log2(IN/4)
{
    int tid = blockIdx.x * blockDim.x + threadIdx.x;
    int stride = gridDim.x * blockDim.x;
    for (int i = tid; i < n4; i += stride) {
        int4 v = w4[i];
        float s = scale[i >> row_shift];
        float4 o;
        o.x = (float)v.x * s;
        o.y = (float)v.y * s;
        o.z = (float)v.z * s;
        o.w = (float)v.w * s;
        out4[i] = o;
    }
}

extern "C" void kernel_launch(void* const* d_in, const int* in_sizes, int n_in,
                              void* d_out, int out_size, void* d_ws, size_t ws_size,
                              hipStream_t stream) {
    const int4* w4 = (const int4*)d_in[0];       // int32 weights, vectorized x4
    const float* scale = (const float*)d_in[1];  // per-row scales
    float4* out4 = (float4*)d_out;

    const int n_weights = in_sizes[0];           // OUT * IN
    const int n_rows    = in_sizes[1];           // OUT
    const int in_per_row = n_weights / n_rows;   // IN
    const int groups_per_row = in_per_row / 4;   // IN/4 (power of two here)
    const int row_shift = __builtin_ctz(groups_per_row);
    const int n4 = n_weights / 4;

    const int block = 256;
    int grid = (n4 + block - 1) / block;
    const int max_grid = 2048;                   // 256 CU x 8 blocks, grid-stride the rest
    if (grid > max_grid) grid = max_grid;

    decompress_int8_sym_kernel<<<grid, block, 0, stream>>>(w4, scale, out4, n4, row_shift);
}